// Round 1
// baseline (1110.901 us; speedup 1.0000x reference)
//
#include <hip/hip_runtime.h>

typedef __bf16 bf16_t;
typedef __bf16 bf16x4 __attribute__((ext_vector_type(4)));
typedef __bf16 bf16x8 __attribute__((ext_vector_type(8)));
typedef float  f32x4  __attribute__((ext_vector_type(4)));

#define MFMA16(a, b, c) __builtin_amdgcn_mfma_f32_16x16x32_bf16((a), (b), (c), 0, 0, 0)

// 28^-0.5
#define ATT_SCALE 0.1889822365046136f

__device__ __forceinline__ bf16x8 load8_masked(const bf16_t* p, bool full) {
  bf16x4 lo = *reinterpret_cast<const bf16x4*>(p);
  bf16x4 hi = {};
  if (full) hi = *reinterpret_cast<const bf16x4*>(p + 4);
  bf16x8 r;
  r[0] = lo[0]; r[1] = lo[1]; r[2] = lo[2]; r[3] = lo[3];
  r[4] = hi[0]; r[5] = hi[1]; r[6] = hi[2]; r[7] = hi[3];
  return r;
}

// ---------------- K0: weights -> transposed bf16 ----------------
__global__ __launch_bounds__(256) void prep_w(
    const float* __restrict__ Wq, const float* __restrict__ Wkv,
    const float* __restrict__ Wo,
    bf16_t* __restrict__ wqt, bf16_t* __restrict__ wkvt, bf16_t* __restrict__ wot) {
  const int id = blockIdx.x * 256 + threadIdx.x;
  if (id < 224 * 224) {
    const int n = id / 224, kk = id % 224;
    wqt[id] = (bf16_t)Wq[kk * 224 + n];
  } else if (id < 224 * 224 + 448 * 224) {
    const int t = id - 224 * 224;
    const int n = t / 224, kk = t % 224;
    wkvt[t] = (bf16_t)Wkv[kk * 448 + n];
  } else {
    const int t = id - (224 * 224 + 448 * 224);
    const int n = t / 224, kk = t % 224;
    wot[t] = (bf16_t)Wo[kk * 224 + n];
  }
}

// ---------------- K1: QKV projection GEMM ----------------
// grid 2048: blk -> 128 tokens (2 windows) in window-partitioned order.
// Writes q/k/v bf16 laid out [b][win][pos][224].
__global__ __launch_bounds__(256) void qkv_gemm(
    const float* __restrict__ x, const bf16_t* __restrict__ wqt,
    const bf16_t* __restrict__ wkvt,
    bf16_t* __restrict__ q, bf16_t* __restrict__ k, bf16_t* __restrict__ v) {
  __shared__ bf16_t xs[128][240];
  __shared__ bf16_t wls[224][40];
  const int tid = threadIdx.x;
  const int blk = blockIdx.x;
  {
    const int b = blk >> 3;
    for (int idx = tid; idx < 128 * 56; idx += 256) {
      const int r = idx / 56, c4 = idx % 56;
      const int win = ((blk & 7) << 1) | (r >> 6);
      const int p = r & 63;
      const int hh = ((win >> 2) << 3) | (p >> 3);
      const int ww = ((win & 3) << 3) | (p & 7);
      const float4 f = *reinterpret_cast<const float4*>(
          x + (size_t)((b * 32 + hh) * 32 + ww) * 224 + c4 * 4);
      bf16x4 o;
      o[0] = (bf16_t)f.x; o[1] = (bf16_t)f.y; o[2] = (bf16_t)f.z; o[3] = (bf16_t)f.w;
      *reinterpret_cast<bf16x4*>(&xs[r][c4 * 4]) = o;
    }
  }
  const int lane = tid & 63;
  const int col = lane & 15, g = lane >> 4;
  const int wid = tid >> 6;
  const int wr = wid >> 1, wc = wid & 1;
  const f32x4 vzero = {0.f, 0.f, 0.f, 0.f};
  __syncthreads();
  for (int chunk = 0; chunk < 3; ++chunk) {
    const bf16_t* wt = (chunk == 0) ? wqt : ((chunk == 1) ? wkvt : (wkvt + 224 * 224));
    bf16_t* dst = (chunk == 0) ? q : ((chunk == 1) ? k : v);
    f32x4 acc[4][7];
#pragma unroll
    for (int ti = 0; ti < 4; ++ti)
#pragma unroll
      for (int tj = 0; tj < 7; ++tj) acc[ti][tj] = vzero;
    for (int ks = 0; ks < 7; ++ks) {
      for (int idx = tid; idx < 224 * 4; idx += 256) {
        const int n = idx >> 2, part = idx & 3;
        *reinterpret_cast<uint4*>(&wls[n][part * 8]) =
            *reinterpret_cast<const uint4*>(wt + n * 224 + ks * 32 + part * 8);
      }
      __syncthreads();
      bf16x8 af[4];
#pragma unroll
      for (int ti = 0; ti < 4; ++ti)
        af[ti] = *reinterpret_cast<const bf16x8*>(&xs[wr * 64 + ti * 16 + col][ks * 32 + g * 8]);
#pragma unroll
      for (int tj = 0; tj < 7; ++tj) {
        const bf16x8 bfr = *reinterpret_cast<const bf16x8*>(&wls[wc * 112 + tj * 16 + col][g * 8]);
#pragma unroll
        for (int ti = 0; ti < 4; ++ti)
          acc[ti][tj] = MFMA16(af[ti], bfr, acc[ti][tj]);
      }
      __syncthreads();
    }
    const size_t base = (size_t)blk * 128;
#pragma unroll
    for (int ti = 0; ti < 4; ++ti)
#pragma unroll
      for (int tj = 0; tj < 7; ++tj)
#pragma unroll
        for (int r = 0; r < 4; ++r) {
          const int row = wr * 64 + ti * 16 + g * 4 + r;
          const int cn = wc * 112 + tj * 16 + col;
          dst[(base + row) * 224 + cn] = (bf16_t)acc[ti][tj][r];
        }
  }
}

// ---------------- K2a: branch-1 attention (64 tokens/window) ----------------
// grid 4096 = (b,win); wave = head 0..3 (channels 28h .. 28h+27).
__global__ __launch_bounds__(256) void attn1(
    const bf16_t* __restrict__ q, const bf16_t* __restrict__ k,
    const bf16_t* __restrict__ v, const float* __restrict__ pos1,
    bf16_t* __restrict__ ao) {
  __shared__ bf16_t Vt[4][32][72];
  __shared__ bf16_t Pl[4][64][72];
  const int tid = threadIdx.x, blk = blockIdx.x;
  const int wid = tid >> 6, lane = tid & 63;
  const int col = lane & 15, g = lane >> 4;
  const size_t rowbase = (size_t)blk * 64;
  // stage V transposed + rotated: Vt[ch][j] = V[(j+1)%64][ch]
  {
    const bf16_t* src = v + (rowbase + lane) * 224 + 28 * wid;
    const int j = (lane + 63) & 63;
#pragma unroll
    for (int c = 0; c < 28; c += 4) {
      const bf16x4 d = *reinterpret_cast<const bf16x4*>(src + c);
      Vt[wid][c + 0][j] = d[0]; Vt[wid][c + 1][j] = d[1];
      Vt[wid][c + 2][j] = d[2]; Vt[wid][c + 3][j] = d[3];
    }
#pragma unroll
    for (int c = 28; c < 32; ++c) Vt[wid][c][lane] = (bf16_t)0.f;
  }
  // Q/K fragments direct from global (d=28 zero-padded to 32)
  bf16x8 aQ[4], bK[4];
#pragma unroll
  for (int t = 0; t < 4; ++t) {
    const size_t off = (rowbase + t * 16 + col) * 224 + 28 * wid + 8 * g;
    aQ[t] = load8_masked(q + off, g < 3);
    bK[t] = load8_masked(k + off, g < 3);
  }
  const f32x4 vzero = {0.f, 0.f, 0.f, 0.f};
  f32x4 s[4][4];
#pragma unroll
  for (int ti = 0; ti < 4; ++ti)
#pragma unroll
    for (int tj = 0; tj < 4; ++tj)
      s[ti][tj] = MFMA16(aQ[ti], bK[tj], vzero);
  const float* pe = pos1 + wid * 4096;
#pragma unroll
  for (int ti = 0; ti < 4; ++ti)
#pragma unroll
    for (int tj = 0; tj < 4; ++tj)
#pragma unroll
      for (int r = 0; r < 4; ++r)
        s[ti][tj][r] = s[ti][tj][r] * ATT_SCALE +
                       pe[(ti * 16 + g * 4 + r) * 64 + tj * 16 + col];
  // row softmax (row = 16*ti + 4*g + r ; cols across tj regs and 16 lanes)
#pragma unroll
  for (int ti = 0; ti < 4; ++ti) {
#pragma unroll
    for (int r = 0; r < 4; ++r) {
      float m = fmaxf(fmaxf(s[ti][0][r], s[ti][1][r]), fmaxf(s[ti][2][r], s[ti][3][r]));
#pragma unroll
      for (int d = 1; d < 16; d <<= 1) m = fmaxf(m, __shfl_xor(m, d));
      float sum = 0.f;
#pragma unroll
      for (int tj = 0; tj < 4; ++tj) {
        const float e = __expf(s[ti][tj][r] - m);
        s[ti][tj][r] = e; sum += e;
      }
#pragma unroll
      for (int d = 1; d < 16; d <<= 1) sum += __shfl_xor(sum, d);
      const float inv = 1.f / sum;
#pragma unroll
      for (int tj = 0; tj < 4; ++tj) s[ti][tj][r] *= inv;
    }
  }
  // P -> LDS (row-major, k-contiguous for A-fragments)
#pragma unroll
  for (int ti = 0; ti < 4; ++ti)
#pragma unroll
    for (int tj = 0; tj < 4; ++tj)
#pragma unroll
      for (int r = 0; r < 4; ++r)
        Pl[wid][ti * 16 + g * 4 + r][tj * 16 + col] = (bf16_t)s[ti][tj][r];
  __syncthreads();
  // O = P * V' ; write rows rotated by +1
#pragma unroll
  for (int ti = 0; ti < 4; ++ti)
#pragma unroll
    for (int t2 = 0; t2 < 2; ++t2) {
      f32x4 o = vzero;
#pragma unroll
      for (int ks = 0; ks < 2; ++ks) {
        const bf16x8 aP = *reinterpret_cast<const bf16x8*>(&Pl[wid][ti * 16 + col][ks * 32 + g * 8]);
        const bf16x8 bV = *reinterpret_cast<const bf16x8*>(&Vt[wid][t2 * 16 + col][ks * 32 + g * 8]);
        o = MFMA16(aP, bV, o);
      }
      const int ch = t2 * 16 + col;
      if (ch < 28) {
#pragma unroll
        for (int r = 0; r < 4; ++r) {
          const int i = ti * 16 + g * 4 + r;
          ao[(rowbase + ((i + 1) & 63)) * 224 + 28 * wid + ch] = (bf16_t)o[r];
        }
      }
    }
}

// ---------------- K2b: branch-2 attention (16 windows per pos) ----------------
// grid 4096 = (b, pos-group of 4); wave = one pos, loops heads 4..7.
__global__ __launch_bounds__(256) void attn2(
    const bf16_t* __restrict__ q, const bf16_t* __restrict__ k,
    const bf16_t* __restrict__ v, const float* __restrict__ pos2,
    bf16_t* __restrict__ ao) {
  __shared__ bf16_t Vt2[4][32][40];
  __shared__ bf16_t P2[4][16][40];
  const int tid = threadIdx.x, blk = blockIdx.x;
  const int wid = tid >> 6, lane = tid & 63;
  const int col = lane & 15, g = lane >> 4;
  const int b = blk >> 4;
  const int pos = (blk & 15) * 4 + wid;
  {
    unsigned short* z1 = reinterpret_cast<unsigned short*>(&Vt2[wid][0][0]);
    for (int i = lane; i < 32 * 40; i += 64) z1[i] = 0;
    unsigned short* z2 = reinterpret_cast<unsigned short*>(&P2[wid][0][0]);
    for (int i = lane; i < 16 * 40; i += 64) z2[i] = 0;
  }
  __syncthreads();
  const f32x4 vzero = {0.f, 0.f, 0.f, 0.f};
  for (int h = 0; h < 4; ++h) {
    // stage Vt2[ch][j] = V[(j+1)%16][ch]
    {
      const bf16_t* src = v + ((size_t)(b * 16 + col) * 64 + pos) * 224 + 112 + 28 * h + 7 * g;
      const int jd = (col + 15) & 15;
#pragma unroll
      for (int i = 0; i < 7; ++i) Vt2[wid][7 * g + i][jd] = src[i];
    }
    const size_t off = ((size_t)(b * 16 + col) * 64 + pos) * 224 + 112 + 28 * h + 8 * g;
    const bf16x8 aQ = load8_masked(q + off, g < 3);
    const bf16x8 bK = load8_masked(k + off, g < 3);
    f32x4 s = MFMA16(aQ, bK, vzero);
    const float* pe = pos2 + h * 256;
#pragma unroll
    for (int r = 0; r < 4; ++r)
      s[r] = s[r] * ATT_SCALE + pe[(g * 4 + r) * 16 + col];
#pragma unroll
    for (int r = 0; r < 4; ++r) {
      float m = s[r];
#pragma unroll
      for (int d = 1; d < 16; d <<= 1) m = fmaxf(m, __shfl_xor(m, d));
      const float e = __expf(s[r] - m);
      float sum = e;
#pragma unroll
      for (int d = 1; d < 16; d <<= 1) sum += __shfl_xor(sum, d);
      s[r] = e / sum;
    }
#pragma unroll
    for (int r = 0; r < 4; ++r) P2[wid][g * 4 + r][col] = (bf16_t)s[r];
    __syncthreads();
    const bf16x8 aP = *reinterpret_cast<const bf16x8*>(&P2[wid][col][g * 8]);
#pragma unroll
    for (int t2 = 0; t2 < 2; ++t2) {
      const bf16x8 bV = *reinterpret_cast<const bf16x8*>(&Vt2[wid][t2 * 16 + col][g * 8]);
      const f32x4 o = MFMA16(aP, bV, vzero);
      const int ch = t2 * 16 + col;
      if (ch < 28) {
#pragma unroll
        for (int r = 0; r < 4; ++r) {
          const int wo = ((g * 4 + r) + 1) & 15;
          ao[((size_t)(b * 16 + wo) * 64 + pos) * 224 + 112 + 28 * h + ch] = (bf16_t)o[r];
        }
      }
    }
    __syncthreads();
  }
}

// ---------------- K3: output projection + bias + window merge ----------------
__global__ __launch_bounds__(256) void out_gemm(
    const bf16_t* __restrict__ ao, const bf16_t* __restrict__ wot,
    const float* __restrict__ bo, float* __restrict__ out) {
  __shared__ bf16_t xs[128][240];
  __shared__ bf16_t wls[224][40];
  const int tid = threadIdx.x, blk = blockIdx.x;
  for (int idx = tid; idx < 128 * 28; idx += 256) {
    const int r = idx / 28, sg = idx % 28;
    *reinterpret_cast<uint4*>(&xs[r][sg * 8]) =
        *reinterpret_cast<const uint4*>(ao + ((size_t)blk * 128 + r) * 224 + sg * 8);
  }
  const int lane = tid & 63;
  const int col = lane & 15, g = lane >> 4;
  const int wid = tid >> 6;
  const int wr = wid >> 1, wc = wid & 1;
  const f32x4 vzero = {0.f, 0.f, 0.f, 0.f};
  f32x4 acc[4][7];
#pragma unroll
  for (int ti = 0; ti < 4; ++ti)
#pragma unroll
    for (int tj = 0; tj < 7; ++tj) acc[ti][tj] = vzero;
  __syncthreads();
  for (int ks = 0; ks < 7; ++ks) {
    for (int idx = tid; idx < 224 * 4; idx += 256) {
      const int n = idx >> 2, part = idx & 3;
      *reinterpret_cast<uint4*>(&wls[n][part * 8]) =
          *reinterpret_cast<const uint4*>(wot + n * 224 + ks * 32 + part * 8);
    }
    __syncthreads();
    bf16x8 af[4];
#pragma unroll
    for (int ti = 0; ti < 4; ++ti)
      af[ti] = *reinterpret_cast<const bf16x8*>(&xs[wr * 64 + ti * 16 + col][ks * 32 + g * 8]);
#pragma unroll
    for (int tj = 0; tj < 7; ++tj) {
      const bf16x8 bfr = *reinterpret_cast<const bf16x8*>(&wls[wc * 112 + tj * 16 + col][g * 8]);
#pragma unroll
      for (int ti = 0; ti < 4; ++ti)
        acc[ti][tj] = MFMA16(af[ti], bfr, acc[ti][tj]);
    }
    __syncthreads();
  }
  float bias[7];
#pragma unroll
  for (int tj = 0; tj < 7; ++tj) bias[tj] = bo[wc * 112 + tj * 16 + col];
  const int b = blk >> 3;
#pragma unroll
  for (int ti = 0; ti < 4; ++ti)
#pragma unroll
    for (int tj = 0; tj < 7; ++tj)
#pragma unroll
      for (int r = 0; r < 4; ++r) {
        const int row = wr * 64 + ti * 16 + g * 4 + r;
        const int cn = wc * 112 + tj * 16 + col;
        const int win = ((blk & 7) << 1) | (row >> 6);
        const int p = row & 63;
        const int hh = ((win >> 2) << 3) | (p >> 3);
        const int ww = ((win & 3) << 3) | (p & 7);
        out[(size_t)((b * 32 + hh) * 32 + ww) * 224 + cn] = acc[ti][tj][r] + bias[tj];
      }
}

extern "C" void kernel_launch(void* const* d_in, const int* in_sizes, int n_in,
                              void* d_out, int out_size, void* d_ws, size_t ws_size,
                              hipStream_t stream) {
  const float* x   = (const float*)d_in[0];
  const float* Wq  = (const float*)d_in[1];
  const float* Wkv = (const float*)d_in[2];
  const float* Wo  = (const float*)d_in[3];
  const float* bo  = (const float*)d_in[4];
  const float* p1  = (const float*)d_in[5];
  const float* p2  = (const float*)d_in[6];
  char* w = (char*)d_ws;
  bf16_t* q_ws  = (bf16_t*)(w);
  bf16_t* k_ws  = (bf16_t*)(w + 117440512);
  bf16_t* v_ws  = (bf16_t*)(w + 234881024);
  bf16_t* ao_ws = (bf16_t*)(w + 352321536);
  bf16_t* wqt   = (bf16_t*)(w + 469762048);
  bf16_t* wkvt  = (bf16_t*)(w + 469862400);
  bf16_t* wot   = (bf16_t*)(w + 470063104);

  prep_w<<<784, 256, 0, stream>>>(Wq, Wkv, Wo, wqt, wkvt, wot);
  qkv_gemm<<<2048, 256, 0, stream>>>(x, wqt, wkvt, q_ws, k_ws, v_ws);
  attn1<<<4096, 256, 0, stream>>>(q_ws, k_ws, v_ws, p1, ao_ws);
  attn2<<<4096, 256, 0, stream>>>(q_ws, k_ws, v_ws, p2, ao_ws);
  out_gemm<<<2048, 256, 0, stream>>>(ao_ws, wot, bo, (float*)d_out);
}

// Round 3
// 1009.805 us; speedup vs baseline: 1.1001x; 1.1001x over previous
//
#include <hip/hip_runtime.h>

typedef __bf16 bf16_t;
typedef __bf16 bf16x4 __attribute__((ext_vector_type(4)));
typedef __bf16 bf16x8 __attribute__((ext_vector_type(8)));
typedef float  f32x4  __attribute__((ext_vector_type(4)));

#define MFMA16(a, b, c) __builtin_amdgcn_mfma_f32_16x16x32_bf16((a), (b), (c), 0, 0, 0)

// 28^-0.5
#define ATT_SCALE 0.1889822365046136f

__device__ __forceinline__ bf16x8 load8_masked(const bf16_t* p, bool full) {
  bf16x4 lo = *reinterpret_cast<const bf16x4*>(p);
  bf16x4 hi = {};
  if (full) hi = *reinterpret_cast<const bf16x4*>(p + 4);
  bf16x8 r;
  r[0] = lo[0]; r[1] = lo[1]; r[2] = lo[2]; r[3] = lo[3];
  r[4] = hi[0]; r[5] = hi[1]; r[6] = hi[2]; r[7] = hi[3];
  return r;
}

// ---------------- K0: weights -> fragment-swizzled bf16 ----------------
// Layout per 224x224 chunk: elem[((ks*14 + nt)*64 + lane)*8 + e] =
//   W[k = ks*32 + (lane>>4)*8 + e][n = nt*16 + (lane&15)]
// so a wave's B-fragment load is one coalesced 1KB dwordx4 read.
__global__ __launch_bounds__(256) void prep_w(
    const float* __restrict__ Wq, const float* __restrict__ Wkv,
    const float* __restrict__ Wo,
    bf16_t* __restrict__ wsw_qkv, bf16_t* __restrict__ wsw_o) {
  const int id = blockIdx.x * 256 + threadIdx.x;  // 98*256 = 25088 slots
  const int buf = id / 6272;                      // 0,1,2 = qkv chunks; 3 = wo
  const int rem = id % 6272;
  const int ks = rem / 896, rem2 = rem % 896;
  const int nt = rem2 / 64, lane = rem2 % 64;
  const int col = lane & 15, g = lane >> 4;
  const int n = nt * 16 + col;
  const int k0 = ks * 32 + g * 8;
  const float* src;
  int stride;
  if (buf == 0)      { src = Wq + n;        stride = 224; }
  else if (buf == 1) { src = Wkv + n;       stride = 448; }
  else if (buf == 2) { src = Wkv + 224 + n; stride = 448; }
  else               { src = Wo + n;        stride = 224; }
  bf16x8 o;
#pragma unroll
  for (int e = 0; e < 8; ++e) o[e] = (bf16_t)src[(size_t)(k0 + e) * stride];
  bf16_t* dst = (buf < 3) ? (wsw_qkv + buf * 100352) : wsw_o;
  *reinterpret_cast<bf16x8*>(dst + ((ks * 14 + nt) * 64 + lane) * 8) = o;
}

// ---------------- K1: QKV projection GEMM ----------------
// grid 12288 = (mtile 0..4095) * 3 + chunk. Block: 64 tokens x 224 cols.
// Weights read directly from L2 (fragment-swizzled), no weight LDS, 1 barrier.
__global__ __launch_bounds__(256, 4) void qkv_gemm(
    const float* __restrict__ x, const bf16_t* __restrict__ wsw,
    bf16_t* __restrict__ q, bf16_t* __restrict__ k, bf16_t* __restrict__ v) {
  __shared__ bf16_t xs[64][232];
  const int tid = threadIdx.x;
  const int blk = blockIdx.x;
  const int mt = blk / 3, chunk = blk % 3;
  const int b = mt >> 4, win = mt & 15;
  for (int idx = tid; idx < 64 * 56; idx += 256) {
    const int r = idx / 56, c4 = idx % 56;
    const int hh = ((win >> 2) << 3) | (r >> 3);
    const int ww = ((win & 3) << 3) | (r & 7);
    const float4 f = *reinterpret_cast<const float4*>(
        x + (size_t)((b * 32 + hh) * 32 + ww) * 224 + c4 * 4);
    bf16x4 o;
    o[0] = (bf16_t)f.x; o[1] = (bf16_t)f.y; o[2] = (bf16_t)f.z; o[3] = (bf16_t)f.w;
    *reinterpret_cast<bf16x4*>(&xs[r][c4 * 4]) = o;
  }
  const int lane = tid & 63, wid = tid >> 6;
  const int col = lane & 15, g = lane >> 4;
  const int wr = wid >> 1, wc = wid & 1;
  const bf16_t* wt = wsw + chunk * 100352;
  bf16_t* dst = (chunk == 0) ? q : ((chunk == 1) ? k : v);
  f32x4 acc[2][7];
  const f32x4 vzero = {0.f, 0.f, 0.f, 0.f};
#pragma unroll
  for (int ti = 0; ti < 2; ++ti)
#pragma unroll
    for (int tj = 0; tj < 7; ++tj) acc[ti][tj] = vzero;
  __syncthreads();
#pragma unroll
  for (int ks = 0; ks < 7; ++ks) {
    bf16x8 af0 = *reinterpret_cast<const bf16x8*>(&xs[wr * 32 + col][ks * 32 + g * 8]);
    bf16x8 af1 = *reinterpret_cast<const bf16x8*>(&xs[wr * 32 + 16 + col][ks * 32 + g * 8]);
#pragma unroll
    for (int tj = 0; tj < 7; ++tj) {
      const bf16x8 bfr = *reinterpret_cast<const bf16x8*>(
          wt + (((ks * 14) + wc * 7 + tj) * 64 + lane) * 8);
      acc[0][tj] = MFMA16(af0, bfr, acc[0][tj]);
      acc[1][tj] = MFMA16(af1, bfr, acc[1][tj]);
    }
  }
  const size_t base = (size_t)mt * 64;
#pragma unroll
  for (int ti = 0; ti < 2; ++ti)
#pragma unroll
    for (int tj = 0; tj < 7; ++tj)
#pragma unroll
      for (int r = 0; r < 4; ++r) {
        const int row = wr * 32 + ti * 16 + g * 4 + r;
        const int cn = wc * 112 + tj * 16 + col;
        dst[(base + row) * 224 + cn] = (bf16_t)acc[ti][tj][r];
      }
}

// ---------------- K2a: branch-1 attention (64 tokens/window) ----------------
__global__ __launch_bounds__(256) void attn1(
    const bf16_t* __restrict__ q, const bf16_t* __restrict__ k,
    const bf16_t* __restrict__ v, const float* __restrict__ pos1,
    bf16_t* __restrict__ ao) {
  __shared__ bf16_t Vt[4][32][72];
  __shared__ bf16_t Pl[4][64][72];
  const int tid = threadIdx.x, blk = blockIdx.x;
  const int wid = tid >> 6, lane = tid & 63;
  const int col = lane & 15, g = lane >> 4;
  const size_t rowbase = (size_t)blk * 64;
  {
    const bf16_t* src = v + (rowbase + lane) * 224 + 28 * wid;
    const int j = (lane + 63) & 63;
#pragma unroll
    for (int c = 0; c < 28; c += 4) {
      const bf16x4 d = *reinterpret_cast<const bf16x4*>(src + c);
      Vt[wid][c + 0][j] = d[0]; Vt[wid][c + 1][j] = d[1];
      Vt[wid][c + 2][j] = d[2]; Vt[wid][c + 3][j] = d[3];
    }
#pragma unroll
    for (int c = 28; c < 32; ++c) Vt[wid][c][lane] = (bf16_t)0.f;
  }
  bf16x8 aQ[4], bK[4];
#pragma unroll
  for (int t = 0; t < 4; ++t) {
    const size_t off = (rowbase + t * 16 + col) * 224 + 28 * wid + 8 * g;
    aQ[t] = load8_masked(q + off, g < 3);
    bK[t] = load8_masked(k + off, g < 3);
  }
  const f32x4 vzero = {0.f, 0.f, 0.f, 0.f};
  f32x4 s[4][4];
#pragma unroll
  for (int ti = 0; ti < 4; ++ti)
#pragma unroll
    for (int tj = 0; tj < 4; ++tj)
      s[ti][tj] = MFMA16(aQ[ti], bK[tj], vzero);
  const float* pe = pos1 + wid * 4096;
#pragma unroll
  for (int ti = 0; ti < 4; ++ti)
#pragma unroll
    for (int tj = 0; tj < 4; ++tj)
#pragma unroll
      for (int r = 0; r < 4; ++r)
        s[ti][tj][r] = s[ti][tj][r] * ATT_SCALE +
                       pe[(ti * 16 + g * 4 + r) * 64 + tj * 16 + col];
#pragma unroll
  for (int ti = 0; ti < 4; ++ti) {
#pragma unroll
    for (int r = 0; r < 4; ++r) {
      float m = fmaxf(fmaxf(s[ti][0][r], s[ti][1][r]), fmaxf(s[ti][2][r], s[ti][3][r]));
#pragma unroll
      for (int d = 1; d < 16; d <<= 1) m = fmaxf(m, __shfl_xor(m, d));
      float sum = 0.f;
#pragma unroll
      for (int tj = 0; tj < 4; ++tj) {
        const float e = __expf(s[ti][tj][r] - m);
        s[ti][tj][r] = e; sum += e;
      }
#pragma unroll
      for (int d = 1; d < 16; d <<= 1) sum += __shfl_xor(sum, d);
      const float inv = 1.f / sum;
#pragma unroll
      for (int tj = 0; tj < 4; ++tj) s[ti][tj][r] *= inv;
    }
  }
#pragma unroll
  for (int ti = 0; ti < 4; ++ti)
#pragma unroll
    for (int tj = 0; tj < 4; ++tj)
#pragma unroll
      for (int r = 0; r < 4; ++r)
        Pl[wid][ti * 16 + g * 4 + r][tj * 16 + col] = (bf16_t)s[ti][tj][r];
  __syncthreads();
#pragma unroll
  for (int ti = 0; ti < 4; ++ti)
#pragma unroll
    for (int t2 = 0; t2 < 2; ++t2) {
      f32x4 o = vzero;
#pragma unroll
      for (int ks = 0; ks < 2; ++ks) {
        const bf16x8 aP = *reinterpret_cast<const bf16x8*>(&Pl[wid][ti * 16 + col][ks * 32 + g * 8]);
        const bf16x8 bV = *reinterpret_cast<const bf16x8*>(&Vt[wid][t2 * 16 + col][ks * 32 + g * 8]);
        o = MFMA16(aP, bV, o);
      }
      const int ch = t2 * 16 + col;
      if (ch < 28) {
#pragma unroll
        for (int r = 0; r < 4; ++r) {
          const int i = ti * 16 + g * 4 + r;
          ao[(rowbase + ((i + 1) & 63)) * 224 + 28 * wid + ch] = (bf16_t)o[r];
        }
      }
    }
}

// ---------------- K2b: branch-2 attention ----------------
__global__ __launch_bounds__(256) void attn2(
    const bf16_t* __restrict__ q, const bf16_t* __restrict__ k,
    const bf16_t* __restrict__ v, const float* __restrict__ pos2,
    bf16_t* __restrict__ ao) {
  __shared__ bf16_t Vt2[4][32][40];
  __shared__ bf16_t P2[4][16][40];
  const int tid = threadIdx.x, blk = blockIdx.x;
  const int wid = tid >> 6, lane = tid & 63;
  const int col = lane & 15, g = lane >> 4;
  const int b = blk >> 4;
  const int pos = (blk & 15) * 4 + wid;
  {
    unsigned short* z1 = reinterpret_cast<unsigned short*>(&Vt2[wid][0][0]);
    for (int i = lane; i < 32 * 40; i += 64) z1[i] = 0;
    unsigned short* z2 = reinterpret_cast<unsigned short*>(&P2[wid][0][0]);
    for (int i = lane; i < 16 * 40; i += 64) z2[i] = 0;
  }
  __syncthreads();
  const f32x4 vzero = {0.f, 0.f, 0.f, 0.f};
  for (int h = 0; h < 4; ++h) {
    {
      const bf16_t* src = v + ((size_t)(b * 16 + col) * 64 + pos) * 224 + 112 + 28 * h + 7 * g;
      const int jd = (col + 15) & 15;
#pragma unroll
      for (int i = 0; i < 7; ++i) Vt2[wid][7 * g + i][jd] = src[i];
    }
    const size_t off = ((size_t)(b * 16 + col) * 64 + pos) * 224 + 112 + 28 * h + 8 * g;
    const bf16x8 aQ = load8_masked(q + off, g < 3);
    const bf16x8 bK = load8_masked(k + off, g < 3);
    f32x4 s = MFMA16(aQ, bK, vzero);
    const float* pe = pos2 + h * 256;
#pragma unroll
    for (int r = 0; r < 4; ++r)
      s[r] = s[r] * ATT_SCALE + pe[(g * 4 + r) * 16 + col];
#pragma unroll
    for (int r = 0; r < 4; ++r) {
      float m = s[r];
#pragma unroll
      for (int d = 1; d < 16; d <<= 1) m = fmaxf(m, __shfl_xor(m, d));
      const float e = __expf(s[r] - m);
      float sum = e;
#pragma unroll
      for (int d = 1; d < 16; d <<= 1) sum += __shfl_xor(sum, d);
      s[r] = e / sum;
    }
#pragma unroll
    for (int r = 0; r < 4; ++r) P2[wid][g * 4 + r][col] = (bf16_t)s[r];
    __syncthreads();
    const bf16x8 aP = *reinterpret_cast<const bf16x8*>(&P2[wid][col][g * 8]);
#pragma unroll
    for (int t2 = 0; t2 < 2; ++t2) {
      const bf16x8 bV = *reinterpret_cast<const bf16x8*>(&Vt2[wid][t2 * 16 + col][g * 8]);
      const f32x4 o = MFMA16(aP, bV, vzero);
      const int ch = t2 * 16 + col;
      if (ch < 28) {
#pragma unroll
        for (int r = 0; r < 4; ++r) {
          const int wo = ((g * 4 + r) + 1) & 15;
          ao[((size_t)(b * 16 + wo) * 64 + pos) * 224 + 112 + 28 * h + ch] = (bf16_t)o[r];
        }
      }
    }
    __syncthreads();
  }
}

// ---------------- K3: output projection + bias + window merge ----------------
// grid 4096 = (b, win). Block: 64 tokens x 224 cols. Same no-weight-LDS scheme.
__global__ __launch_bounds__(256, 4) void out_gemm(
    const bf16_t* __restrict__ ao, const bf16_t* __restrict__ wsw,
    const float* __restrict__ bo, float* __restrict__ out) {
  __shared__ bf16_t xs[64][232];
  const int tid = threadIdx.x, blk = blockIdx.x;
  for (int idx = tid; idx < 64 * 28; idx += 256) {
    const int r = idx / 28, sg = idx % 28;
    *reinterpret_cast<uint4*>(&xs[r][sg * 8]) =
        *reinterpret_cast<const uint4*>(ao + ((size_t)blk * 64 + r) * 224 + sg * 8);
  }
  const int lane = tid & 63, wid = tid >> 6;
  const int col = lane & 15, g = lane >> 4;
  const int wr = wid >> 1, wc = wid & 1;
  f32x4 acc[2][7];
  const f32x4 vzero = {0.f, 0.f, 0.f, 0.f};
#pragma unroll
  for (int ti = 0; ti < 2; ++ti)
#pragma unroll
    for (int tj = 0; tj < 7; ++tj) acc[ti][tj] = vzero;
  __syncthreads();
#pragma unroll
  for (int ks = 0; ks < 7; ++ks) {
    bf16x8 af0 = *reinterpret_cast<const bf16x8*>(&xs[wr * 32 + col][ks * 32 + g * 8]);
    bf16x8 af1 = *reinterpret_cast<const bf16x8*>(&xs[wr * 32 + 16 + col][ks * 32 + g * 8]);
#pragma unroll
    for (int tj = 0; tj < 7; ++tj) {
      const bf16x8 bfr = *reinterpret_cast<const bf16x8*>(
          wsw + (((ks * 14) + wc * 7 + tj) * 64 + lane) * 8);
      acc[0][tj] = MFMA16(af0, bfr, acc[0][tj]);
      acc[1][tj] = MFMA16(af1, bfr, acc[1][tj]);
    }
  }
  float bias[7];
#pragma unroll
  for (int tj = 0; tj < 7; ++tj) bias[tj] = bo[wc * 112 + tj * 16 + col];
  const int b = blk >> 4, win = blk & 15;
#pragma unroll
  for (int ti = 0; ti < 2; ++ti)
#pragma unroll
    for (int tj = 0; tj < 7; ++tj)
#pragma unroll
      for (int r = 0; r < 4; ++r) {
        const int p = wr * 32 + ti * 16 + g * 4 + r;
        const int cn = wc * 112 + tj * 16 + col;
        const int hh = ((win >> 2) << 3) | (p >> 3);
        const int ww = ((win & 3) << 3) | (p & 7);
        out[(size_t)((b * 32 + hh) * 32 + ww) * 224 + cn] = acc[ti][tj][r] + bias[tj];
      }
}

extern "C" void kernel_launch(void* const* d_in, const int* in_sizes, int n_in,
                              void* d_out, int out_size, void* d_ws, size_t ws_size,
                              hipStream_t stream) {
  const float* x   = (const float*)d_in[0];
  const float* Wq  = (const float*)d_in[1];
  const float* Wkv = (const float*)d_in[2];
  const float* Wo  = (const float*)d_in[3];
  const float* bo  = (const float*)d_in[4];
  const float* p1  = (const float*)d_in[5];
  const float* p2  = (const float*)d_in[6];
  char* w = (char*)d_ws;
  bf16_t* q_ws    = (bf16_t*)(w);
  bf16_t* k_ws    = (bf16_t*)(w + 117440512);
  bf16_t* v_ws    = (bf16_t*)(w + 234881024);
  bf16_t* ao_ws   = (bf16_t*)(w + 352321536);
  bf16_t* wsw_qkv = (bf16_t*)(w + 469762048);
  bf16_t* wsw_o   = (bf16_t*)(w + 470063104);

  prep_w<<<98, 256, 0, stream>>>(Wq, Wkv, Wo, wsw_qkv, wsw_o);
  qkv_gemm<<<12288, 256, 0, stream>>>(x, wsw_qkv, q_ws, k_ws, v_ws);
  attn1<<<4096, 256, 0, stream>>>(q_ws, k_ws, v_ws, p1, ao_ws);
  attn2<<<4096, 256, 0, stream>>>(q_ws, k_ws, v_ws, p2, ao_ws);
  out_gemm<<<4096, 256, 0, stream>>>(ao_ws, wsw_o, bo, (float*)d_out);
}